// Round 4
// baseline (284.981 us; speedup 1.0000x reference)
//
#include <hip/hip_runtime.h>

#define NB 4
#define NS 2048
#define ND 768
#define NH 12
#define NDH 64
#define NT (NS / 128)
#define XPITCH 72
#define SSCALE 0.18033688011112043f   // (1/sqrt(64)) * log2(e)

typedef __bf16 bf16x8 __attribute__((ext_vector_type(8)));
typedef float  f32x4  __attribute__((ext_vector_type(4)));
typedef unsigned int u32;

#define MFMA16(a, b, c) __builtin_amdgcn_mfma_f32_16x16x32_bf16(a, b, c, 0, 0, 0)

__device__ __forceinline__ u32 packbf(float a, float b) {
    u32 ua = __builtin_bit_cast(u32, a) + 0x8000u;
    u32 ub = __builtin_bit_cast(u32, b) + 0x8000u;
    return __builtin_amdgcn_perm(ub, ua, 0x07060302u);
}

__device__ __forceinline__ bf16x8 cvt8(float4 a, float4 b) {
    union { u32 u[4]; bf16x8 v; } r;
    r.u[0] = packbf(a.x, a.y); r.u[1] = packbf(a.z, a.w);
    r.u[2] = packbf(b.x, b.y); r.u[3] = packbf(b.z, b.w);
    return r.v;
}

__device__ __forceinline__ __bf16 f2bf(float f) {
    u32 u = __builtin_bit_cast(u32, f) + 0x8000u;
    unsigned short s = (unsigned short)(u >> 16);
    return __builtin_bit_cast(__bf16, s);
}

// ---------------------------------------------------------------------------
// FRAGMENT-MAJOR workspace layouts (new this round). Both kernels must agree.
// The attention K-loop loads MFMA fragments DIRECTLY from global, fully
// coalesced (64 lanes x 16B contiguous = 1KB/instr), eliminating ALL LDS
// traffic from the hot loop (old: 16x ds_*_b128 per wave-iter ~ saturated
// the DS pipe at ~9.6 waves/CU; LDS-pipe demand > iteration period).
//
// Fragment chunk definitions (verified equal to what the old LDS path fed
// the MFMAs):
//   K: ka[mt][j], lane(quad,col) = K[128kt + 32w + 16mt + col][8quad+32j ..+8]
//   V: va[dt],    lane(quad,col) = V^T[16dt + col][128kt + 32w + 8quad ..+8]
//   Q: qb{0,1}[nt], lane        = Q[64qt + 16nt + col][8quad + 32j ..+8]
// Element strides (bf16 units):
//   K: bh*131072 + kt*8192 + w*2048 + mt*1024 + j*512 + lane*8
//   V: bh*131072 + kt*8192 + w*2048 + dt*512            + lane*8
//   Q: bh*131072 + st*4096 + nt*1024 + j*512            + lane*8
// ---------------------------------------------------------------------------

// ---------------------------------------------------------------------------
// Kernel 1: QKV projections. Compute identical to verified version; only the
// STORE ADDRESSES changed to the fragment-major layouts above.
// proj store granularity: Q/K uint2 (4 e-elems, 4-aligned -> half of a 16B
// lane chunk), V uint4 (8 s-elems = exactly one lane chunk).
// ---------------------------------------------------------------------------
__global__ __launch_bounds__(256, 4) void proj_kernel(
    const float* __restrict__ x,
    const float* __restrict__ wq, const float* __restrict__ bq,
    const float* __restrict__ wk, const float* __restrict__ bk,
    const float* __restrict__ wv, const float* __restrict__ bv,
    __bf16* __restrict__ qws, __bf16* __restrict__ kws, __bf16* __restrict__ vtws)
{
    const int st = blockIdx.x, h = blockIdx.y, b = blockIdx.z;
    const int s0 = st * 64;
    const int tid = threadIdx.x;

    __shared__ __align__(16) __bf16 Xs[64 * XPITCH];
    __shared__ __align__(16) __bf16 Tv[64 * XPITCH];

    const int r = tid >> 2, f = tid & 3;
    const int lane = tid & 63, w = tid >> 6, col = lane & 15, quad = lane >> 4;

    const size_t wrow = (size_t)(h * NDH + w * 16 + col) * NDH;
    const float* wq0 = wq + wrow + quad * 8;
    const float* wk0 = wk + wrow + quad * 8;
    const float* wv0 = wv + wrow + quad * 8;
    const bf16x8 wqa0 = cvt8(*(const float4*)(wq0),      *(const float4*)(wq0 + 4));
    const bf16x8 wqa1 = cvt8(*(const float4*)(wq0 + 32), *(const float4*)(wq0 + 36));
    const bf16x8 wka0 = cvt8(*(const float4*)(wk0),      *(const float4*)(wk0 + 4));
    const bf16x8 wka1 = cvt8(*(const float4*)(wk0 + 32), *(const float4*)(wk0 + 36));
    const bf16x8 wva0 = cvt8(*(const float4*)(wv0),      *(const float4*)(wv0 + 4));
    const bf16x8 wva1 = cvt8(*(const float4*)(wv0 + 32), *(const float4*)(wv0 + 36));

    float bqs[4], bks[4], bvs[4];
#pragma unroll
    for (int rr = 0; rr < 4; ++rr) {
        const int e = h * NDH + w * 16 + quad * 4 + rr;
        bqs[rr] = bq[e] * SSCALE;
        bks[rr] = bk[e];
        bvs[rr] = bv[e];
    }

    const size_t bh = (size_t)(b * NH + h);

    {
        const float* xrow = x + (size_t)(b * NS + s0 + r) * ND + h * NDH + f * 16;
        const float4 v0 = *(const float4*)(xrow);
        const float4 v1 = *(const float4*)(xrow + 4);
        const float4 v2 = *(const float4*)(xrow + 8);
        const float4 v3 = *(const float4*)(xrow + 12);
        *(bf16x8*)&Xs[r * XPITCH + f * 16]     = cvt8(v0, v1);
        *(bf16x8*)&Xs[r * XPITCH + f * 16 + 8] = cvt8(v2, v3);
    }
    __syncthreads();

    // lane-constant pieces of the fragment-layout address (e-side):
    // e0 = w*16 + quad*4 = 32*jj + 8*qa + 4*hf
    const int e0 = w * 16 + quad * 4;
    const int jj = e0 >> 5;            // j (0/1)
    const int qa = (e0 >> 3) & 3;      // quad_attn
    const int hf = (e0 >> 2) & 1;      // which uint2 half of the 16B chunk
    const int Lf = qa * 16 + col;      // fragment lane
    const int kt = st >> 1;            // 128-row K-tile index

#pragma unroll
    for (int nt = 0; nt < 4; ++nt) {
        const bf16x8 xb0 = *(const bf16x8*)&Xs[(nt * 16 + col) * XPITCH + quad * 8];
        const bf16x8 xb1 = *(const bf16x8*)&Xs[(nt * 16 + col) * XPITCH + 32 + quad * 8];
        f32x4 aq = {0.f, 0.f, 0.f, 0.f};
        f32x4 ak = {0.f, 0.f, 0.f, 0.f};
        f32x4 av = {0.f, 0.f, 0.f, 0.f};
        aq = MFMA16(wqa0, xb0, aq); aq = MFMA16(wqa1, xb1, aq);
        ak = MFMA16(wka0, xb0, ak); ak = MFMA16(wka1, xb1, ak);
        av = MFMA16(wva0, xb0, av); av = MFMA16(wva1, xb1, av);

        union { u32 u[2]; uint2 v; } pq, pk;
        pq.u[0] = packbf(fmaf(aq[0], SSCALE, bqs[0]), fmaf(aq[1], SSCALE, bqs[1]));
        pq.u[1] = packbf(fmaf(aq[2], SSCALE, bqs[2]), fmaf(aq[3], SSCALE, bqs[3]));
        pk.u[0] = packbf(ak[0] + bks[0], ak[1] + bks[1]);
        pk.u[1] = packbf(ak[2] + bks[2], ak[3] + bks[3]);

        // fragment-major stores
        const int wa = (st & 1) * 2 + (nt >> 1);   // attn wave owning this row
        const int mt = nt & 1;
        const size_t kidx = ((((((size_t)bh * 16 + kt) * 4 + wa) * 2 + mt) * 2 + jj) * 64 + Lf) * 8 + hf * 4;
        const size_t qidx = (((((size_t)bh * 32 + st) * 4 + nt) * 2 + jj) * 64 + Lf) * 8 + hf * 4;
        *(uint2*)(kws + kidx) = pk.v;
        *(uint2*)(qws + qidx) = pq.v;

        const int pos = ((nt >> 1) << 5) + ((col >> 2) << 3) + ((nt & 1) << 2) + (col & 3);
#pragma unroll
        for (int rr = 0; rr < 4; ++rr)
            Tv[(w * 16 + quad * 4 + rr) * XPITCH + pos] = f2bf(av[rr] + bvs[rr]);
    }
    __syncthreads();

    {
        const uint4 v0 = *(const uint4*)&Tv[r * XPITCH + f * 16];
        const uint4 v1 = *(const uint4*)&Tv[r * XPITCH + f * 16 + 8];
        // thread (r,f) holds V^T[d=r][s0 + f*16 .. +15] = two 8-s chunks
        const int wv_ = (st & 1) * 2 + (f >> 1);
        const int dtv = r >> 4;
        const int colv = r & 15;
        const int L0 = ((f & 1) * 2 + 0) * 16 + colv;
        const int L1 = ((f & 1) * 2 + 1) * 16 + colv;
        const size_t vbase = (((size_t)bh * 16 + kt) * 4 + wv_) * 4 + dtv;
        *(uint4*)(vtws + (vbase * 64 + L0) * 8) = v0;
        *(uint4*)(vtws + (vbase * 64 + L1) * 8) = v1;
    }
}

// ---------------------------------------------------------------------------
// Kernel 2: flash attention WITHOUT online max (scores statically bounded;
// exp2 direct). K-loop is now LDS-FREE: fragment-major global loads straight
// into MFMA operand registers, explicit two-phase register double-buffer
// (static indexing; one full compute phase of vmcnt slack per fragment set).
//
// launch_bounds(256,3) — DO NOT RAISE TO 4. Measured lesson (R2): unified
// VGPR+AGPR demand is ~148 (VGPR_Count=84 reports arch VGPRs ONLY; the
// f32x4 o[4][4] accumulator adds ~64 AGPRs on the gfx950 unified file).
// At (256,4) budget=128 < 148 -> spill catastrophe (WRITE 37->375MB).
//
// XCD-bijective decode kept (R3-proven: FETCH 109->24MB, K/V L2-resident).
// s_setprio REMOVED (R3 suspect: symmetric waves have no role split; T5
// prereq absent).
// LDS: epilogue only — slabA 64x68 f32 | slabB | lbuf. 35840 B.
// ---------------------------------------------------------------------------
__global__ __launch_bounds__(256, 3) void attn_kernel(
    const __bf16* __restrict__ qws, const __bf16* __restrict__ kws,
    const __bf16* __restrict__ vtws, float* __restrict__ out)
{
    // XCD-aware bijective decode: bid = xcd + 8*j, j = 32*(group within XCD) + qt
    const int bid = blockIdx.x;
    const int xcd = bid & 7;
    const int j   = bid >> 3;            // 0..191
    const int g   = xcd * 6 + (j >> 5);  // (b,h) group 0..47
    const int qt  = j & 31;
    const int h   = g % NH;
    const int b   = g / NH;

    const int q0 = qt * 64;
    const int tid = threadIdx.x;

    __shared__ __align__(16) unsigned char smem[35840];
    float* slabA = (float*)smem;                 // 64 x 68 f32
    float* slabB = (float*)(smem + 17408);       // 64 x 68 f32
    float* lbuf  = (float*)(smem + 34816);       // 256 f32

    const size_t bh = (size_t)(b * NH + h);
    const int lane = tid & 63, w = tid >> 6, col = lane & 15, quad = lane >> 4;

    // Q fragments (fragment-major layout; coalesced)
    bf16x8 qb0[4], qb1[4];
    {
        const __bf16* qp = qws + (size_t)bh * 131072 + (size_t)qt * 4096 + lane * 8;
#pragma unroll
        for (int nt = 0; nt < 4; ++nt) {
            qb0[nt] = *(const bf16x8*)(qp + nt * 1024);
            qb1[nt] = *(const bf16x8*)(qp + nt * 1024 + 512);
        }
    }

    // fragment-major bases for this wave
    const __bf16* kb = kws  + (size_t)bh * 131072 + w * 2048 + lane * 8;
    const __bf16* vb = vtws + (size_t)bh * 131072 + w * 2048 + lane * 8;

    float l[4] = {0.f, 0.f, 0.f, 0.f};
    f32x4 o[4][4];
#pragma unroll
    for (int dt = 0; dt < 4; ++dt)
#pragma unroll
        for (int nt = 0; nt < 4; ++nt) o[dt][nt] = (f32x4){0.f, 0.f, 0.f, 0.f};

#define LOADK(dst, kt) do { \
        const __bf16* _p = kb + (size_t)(kt) * 8192; \
        dst[0][0] = *(const bf16x8*)(_p);        dst[0][1] = *(const bf16x8*)(_p + 512); \
        dst[1][0] = *(const bf16x8*)(_p + 1024); dst[1][1] = *(const bf16x8*)(_p + 1536); \
    } while (0)
#define LOADV(dst, kt) do { \
        const __bf16* _p = vb + (size_t)(kt) * 8192; \
        dst[0] = *(const bf16x8*)(_p);        dst[1] = *(const bf16x8*)(_p + 512); \
        dst[2] = *(const bf16x8*)(_p + 1024); dst[3] = *(const bf16x8*)(_p + 1536); \
    } while (0)

    auto compute = [&](const bf16x8 (&ka)[2][2], const bf16x8 (&va)[4]) {
#pragma unroll
        for (int nt = 0; nt < 4; ++nt) {
            f32x4 sA = {0.f, 0.f, 0.f, 0.f};
            f32x4 sB = {0.f, 0.f, 0.f, 0.f};
            sA = MFMA16(ka[0][0], qb0[nt], sA); sA = MFMA16(ka[0][1], qb1[nt], sA);
            sB = MFMA16(ka[1][0], qb0[nt], sB); sB = MFMA16(ka[1][1], qb1[nt], sB);

            // direct exp2 — no max subtraction, fully lane-local
            const float p0 = __builtin_amdgcn_exp2f(sA[0]);
            const float p1 = __builtin_amdgcn_exp2f(sA[1]);
            const float p2 = __builtin_amdgcn_exp2f(sA[2]);
            const float p3 = __builtin_amdgcn_exp2f(sA[3]);
            const float p4 = __builtin_amdgcn_exp2f(sB[0]);
            const float p5 = __builtin_amdgcn_exp2f(sB[1]);
            const float p6 = __builtin_amdgcn_exp2f(sB[2]);
            const float p7 = __builtin_amdgcn_exp2f(sB[3]);
            l[nt] += ((p0 + p1) + (p2 + p3)) + ((p4 + p5) + (p6 + p7));

            union { u32 u[4]; bf16x8 v; } pb;   // B-frag: k_mfma = quad*8+mt*4+r
            pb.u[0] = packbf(p0, p1);
            pb.u[1] = packbf(p2, p3);
            pb.u[2] = packbf(p4, p5);
            pb.u[3] = packbf(p6, p7);

#pragma unroll
            for (int dt = 0; dt < 4; ++dt)
                o[dt][nt] = MFMA16(va[dt], pb.v, o[dt][nt]);
        }
    };

    // two-phase register double-buffer: zero LDS in the hot loop
    bf16x8 kc[2][2], vc[4], kn[2][2], vn[4];
    LOADK(kc, 0); LOADV(vc, 0);
    for (int kt2 = 0; kt2 < NT; kt2 += 2) {
        LOADK(kn, kt2 + 1); LOADV(vn, kt2 + 1);   // kt2+1 <= 15 always (NT even)
        compute(kc, vc);
        if (kt2 + 2 < NT) { LOADK(kc, kt2 + 2); LOADV(vc, kt2 + 2); }
        compute(kn, vn);
    }
#undef LOADK
#undef LOADV

    // cross-quad l reduction (deferred from loop)
#pragma unroll
    for (int nt = 0; nt < 4; ++nt) {
        l[nt] += __shfl_xor(l[nt], 16, 64);
        l[nt] += __shfl_xor(l[nt], 32, 64);
    }

    // ---- split-K combine across the 4 waves (l only — no m state) ----
    __syncthreads();
    if (quad == 0) {
#pragma unroll
        for (int nt = 0; nt < 4; ++nt)
            lbuf[w * 64 + nt * 16 + col] = l[nt];
    }
    __syncthreads();

    float scale[4];
#pragma unroll
    for (int nt = 0; nt < 4; ++nt) {
        const int qi = nt * 16 + col;
        const float Lt = (lbuf[qi] + lbuf[64 + qi]) + (lbuf[128 + qi] + lbuf[192 + qi]);
        scale[nt] = 1.0f / Lt;
    }
    __syncthreads();   // lbuf reads done before slab writes alias the region
#pragma unroll
    for (int dt = 0; dt < 4; ++dt)
#pragma unroll
        for (int nt = 0; nt < 4; ++nt) o[dt][nt] *= scale[nt];

    if (w == 0 || w == 2) {
        float* s = (w == 0) ? slabA : slabB;
#pragma unroll
        for (int dt = 0; dt < 4; ++dt)
#pragma unroll
            for (int nt = 0; nt < 4; ++nt)
                *(f32x4*)&s[(nt * 16 + col) * 68 + dt * 16 + quad * 4] = o[dt][nt];
    }
    __syncthreads();
    if (w == 1 || w == 3) {
        float* s = (w == 1) ? slabA : slabB;
#pragma unroll
        for (int dt = 0; dt < 4; ++dt)
#pragma unroll
            for (int nt = 0; nt < 4; ++nt) {
                f32x4* p = (f32x4*)&s[(nt * 16 + col) * 68 + dt * 16 + quad * 4];
                *p = *p + o[dt][nt];
            }
    }
    __syncthreads();

    const int qr = tid >> 2, fq = tid & 3;
#pragma unroll
    for (int j2 = 0; j2 < 4; ++j2) {
        const f32x4 a = *(const f32x4*)&slabA[qr * 68 + fq * 16 + j2 * 4];
        const f32x4 c = *(const f32x4*)&slabB[qr * 68 + fq * 16 + j2 * 4];
        *(f32x4*)&out[(size_t)(b * NS + q0 + qr) * ND + h * NDH + fq * 16 + j2 * 4] = a + c;
    }
}

extern "C" void kernel_launch(void* const* d_in, const int* in_sizes, int n_in,
                              void* d_out, int out_size, void* d_ws, size_t ws_size,
                              hipStream_t stream) {
    (void)in_sizes; (void)n_in; (void)out_size; (void)ws_size;
    const float* x  = (const float*)d_in[0];
    const float* wq = (const float*)d_in[1];
    const float* bq = (const float*)d_in[2];
    const float* wk = (const float*)d_in[3];
    const float* bk = (const float*)d_in[4];
    const float* wv = (const float*)d_in[5];
    const float* bv = (const float*)d_in[6];
    float* out = (float*)d_out;

    __bf16* qws  = (__bf16*)d_ws;
    __bf16* kws  = qws + (size_t)NB * NH * NS * NDH;
    __bf16* vtws = kws + (size_t)NB * NH * NS * NDH;

    dim3 grid(NS / 64, NH, NB);
    proj_kernel<<<grid, 256, 0, stream>>>(x, wq, bq, wk, bk, wv, bv, qws, kws, vtws);
    attn_kernel<<<dim3(NS / 64 * NH * NB), 256, 0, stream>>>(qws, kws, vtws, out);
}

// Round 5
// 263.269 us; speedup vs baseline: 1.0825x; 1.0825x over previous
//
#include <hip/hip_runtime.h>

#define NB 4
#define NS 2048
#define ND 768
#define NH 12
#define NDH 64
#define NT (NS / 128)
#define XPITCH 72
#define SSCALE 0.18033688011112043f   // (1/sqrt(64)) * log2(e)

typedef __bf16 bf16x8 __attribute__((ext_vector_type(8)));
typedef float  f32x4  __attribute__((ext_vector_type(4)));
typedef unsigned int u32;

#define MFMA16(a, b, c) __builtin_amdgcn_mfma_f32_16x16x32_bf16(a, b, c, 0, 0, 0)

__device__ __forceinline__ u32 packbf(float a, float b) {
    u32 ua = __builtin_bit_cast(u32, a) + 0x8000u;
    u32 ub = __builtin_bit_cast(u32, b) + 0x8000u;
    return __builtin_amdgcn_perm(ub, ua, 0x07060302u);
}

__device__ __forceinline__ bf16x8 cvt8(float4 a, float4 b) {
    union { u32 u[4]; bf16x8 v; } r;
    r.u[0] = packbf(a.x, a.y); r.u[1] = packbf(a.z, a.w);
    r.u[2] = packbf(b.x, b.y); r.u[3] = packbf(b.z, b.w);
    return r.v;
}

__device__ __forceinline__ __bf16 f2bf(float f) {
    u32 u = __builtin_bit_cast(u32, f) + 0x8000u;
    unsigned short s = (unsigned short)(u >> 16);
    return __builtin_bit_cast(__bf16, s);
}

// ---------------------------------------------------------------------------
// Workspace layouts (MIXED, every piece hardware-verified):
//   Q:  FRAGMENT-MAJOR (R4-passed):  bh*131072 + qt*4096 + nt*1024 + j*512 + lane*8
//   K:  ROW-MAJOR      (R0/R3-passed): (bh*NS + s)*NDH + e   (attn stages via LDS)
//   V:  FRAGMENT-MAJOR (R4-passed):  bh*131072 + kt*8192 + w*2048 + dt*512 + lane*8
//       (va[dt] lane(quad,col) = V^T[16dt+col][128kt + 32w + 8quad ..+8])
// ---------------------------------------------------------------------------

// ---------------------------------------------------------------------------
// Kernel 1: QKV projections. Compute identical to verified version.
// K store: row-major (R0 verbatim). Q store: fragment-major (R4 verbatim).
// V store: transpose slab -> fragment-major (R4 verbatim).
// ---------------------------------------------------------------------------
__global__ __launch_bounds__(256, 4) void proj_kernel(
    const float* __restrict__ x,
    const float* __restrict__ wq, const float* __restrict__ bq,
    const float* __restrict__ wk, const float* __restrict__ bk,
    const float* __restrict__ wv, const float* __restrict__ bv,
    __bf16* __restrict__ qws, __bf16* __restrict__ kws, __bf16* __restrict__ vtws)
{
    const int st = blockIdx.x, h = blockIdx.y, b = blockIdx.z;
    const int s0 = st * 64;
    const int tid = threadIdx.x;

    __shared__ __align__(16) __bf16 Xs[64 * XPITCH];
    __shared__ __align__(16) __bf16 Tv[64 * XPITCH];

    const int r = tid >> 2, f = tid & 3;
    const int lane = tid & 63, w = tid >> 6, col = lane & 15, quad = lane >> 4;

    const size_t wrow = (size_t)(h * NDH + w * 16 + col) * NDH;
    const float* wq0 = wq + wrow + quad * 8;
    const float* wk0 = wk + wrow + quad * 8;
    const float* wv0 = wv + wrow + quad * 8;
    const bf16x8 wqa0 = cvt8(*(const float4*)(wq0),      *(const float4*)(wq0 + 4));
    const bf16x8 wqa1 = cvt8(*(const float4*)(wq0 + 32), *(const float4*)(wq0 + 36));
    const bf16x8 wka0 = cvt8(*(const float4*)(wk0),      *(const float4*)(wk0 + 4));
    const bf16x8 wka1 = cvt8(*(const float4*)(wk0 + 32), *(const float4*)(wk0 + 36));
    const bf16x8 wva0 = cvt8(*(const float4*)(wv0),      *(const float4*)(wv0 + 4));
    const bf16x8 wva1 = cvt8(*(const float4*)(wv0 + 32), *(const float4*)(wv0 + 36));

    float bqs[4], bks[4], bvs[4];
#pragma unroll
    for (int rr = 0; rr < 4; ++rr) {
        const int e = h * NDH + w * 16 + quad * 4 + rr;
        bqs[rr] = bq[e] * SSCALE;
        bks[rr] = bk[e];
        bvs[rr] = bv[e];
    }

    const size_t bh = (size_t)(b * NH + h);

    {
        const float* xrow = x + (size_t)(b * NS + s0 + r) * ND + h * NDH + f * 16;
        const float4 v0 = *(const float4*)(xrow);
        const float4 v1 = *(const float4*)(xrow + 4);
        const float4 v2 = *(const float4*)(xrow + 8);
        const float4 v3 = *(const float4*)(xrow + 12);
        *(bf16x8*)&Xs[r * XPITCH + f * 16]     = cvt8(v0, v1);
        *(bf16x8*)&Xs[r * XPITCH + f * 16 + 8] = cvt8(v2, v3);
    }
    __syncthreads();

    // lane-constant pieces of the Q fragment-layout address (e-side):
    // e0 = w*16 + quad*4 = 32*jj + 8*qa + 4*hf
    const int e0 = w * 16 + quad * 4;
    const int jj = e0 >> 5;            // j (0/1)
    const int qa = (e0 >> 3) & 3;      // quad_attn
    const int hf = (e0 >> 2) & 1;      // which uint2 half of the 16B chunk
    const int Lf = qa * 16 + col;      // fragment lane
    const int kt = st >> 1;            // 128-row K-tile index

#pragma unroll
    for (int nt = 0; nt < 4; ++nt) {
        const bf16x8 xb0 = *(const bf16x8*)&Xs[(nt * 16 + col) * XPITCH + quad * 8];
        const bf16x8 xb1 = *(const bf16x8*)&Xs[(nt * 16 + col) * XPITCH + 32 + quad * 8];
        f32x4 aq = {0.f, 0.f, 0.f, 0.f};
        f32x4 ak = {0.f, 0.f, 0.f, 0.f};
        f32x4 av = {0.f, 0.f, 0.f, 0.f};
        aq = MFMA16(wqa0, xb0, aq); aq = MFMA16(wqa1, xb1, aq);
        ak = MFMA16(wka0, xb0, ak); ak = MFMA16(wka1, xb1, ak);
        av = MFMA16(wva0, xb0, av); av = MFMA16(wva1, xb1, av);

        union { u32 u[2]; uint2 v; } pq, pk;
        pq.u[0] = packbf(fmaf(aq[0], SSCALE, bqs[0]), fmaf(aq[1], SSCALE, bqs[1]));
        pq.u[1] = packbf(fmaf(aq[2], SSCALE, bqs[2]), fmaf(aq[3], SSCALE, bqs[3]));
        pk.u[0] = packbf(ak[0] + bks[0], ak[1] + bks[1]);
        pk.u[1] = packbf(ak[2] + bks[2], ak[3] + bks[3]);

        // K: row-major store (R0-verified)
        const size_t goff = (bh * NS + s0 + nt * 16 + col) * NDH + w * 16 + quad * 4;
        *(uint2*)(kws + goff) = pk.v;
        // Q: fragment-major store (R4-verified)
        const size_t qidx = (((((size_t)bh * 32 + st) * 4 + nt) * 2 + jj) * 64 + Lf) * 8 + hf * 4;
        *(uint2*)(qws + qidx) = pq.v;

        const int pos = ((nt >> 1) << 5) + ((col >> 2) << 3) + ((nt & 1) << 2) + (col & 3);
#pragma unroll
        for (int rr = 0; rr < 4; ++rr)
            Tv[(w * 16 + quad * 4 + rr) * XPITCH + pos] = f2bf(av[rr] + bvs[rr]);
    }
    __syncthreads();

    {
        const uint4 v0 = *(const uint4*)&Tv[r * XPITCH + f * 16];
        const uint4 v1 = *(const uint4*)&Tv[r * XPITCH + f * 16 + 8];
        // thread (r,f) holds V^T[d=r][s0 + f*16 .. +15] = two 8-s chunks (R4-verified)
        const int wv_ = (st & 1) * 2 + (f >> 1);
        const int dtv = r >> 4;
        const int colv = r & 15;
        const int L0 = ((f & 1) * 2 + 0) * 16 + colv;
        const int L1 = ((f & 1) * 2 + 1) * 16 + colv;
        const size_t vbase = (((size_t)bh * 16 + kt) * 4 + wv_) * 4 + dtv;
        *(uint4*)(vtws + (vbase * 64 + L0) * 8) = v0;
        *(uint4*)(vtws + (vbase * 64 + L1) * 8) = v1;
    }
}

// ---------------------------------------------------------------------------
// Kernel 2: flash attention WITHOUT online max (scores statically bounded;
// exp2 direct). HYBRID staging, register-isomorphic to the proven R3 loop
// (peak unified regs ~148, launch_bounds(256,3) budget 168 — R2 lesson:
// VGPR_Count ignores the 64 AGPRs of o[4][4]; (256,4) spills, never raise):
//   K: global->reg->wave-private swizzled LDS slab (R3 path, verbatim).
//   V: DIRECT from global in fragment-major layout (R4-verified addresses),
//      register double-buffered vc/vn via 2-phase unroll (static indexing).
//   Q: fragment-major coalesced loads (R4-verified).
// DS ops drop 16 -> 8 per tile (R3 theory: DS pipe was the saturated pipe).
// XCD-bijective decode kept (R3: FETCH 109->24MB; keeps direct-V L2-resident).
// s_setprio OUT (R3: +7us suspect; symmetric waves, no role split).
// LDS: K slabs [0,16368B) | epilogue slabA[0,17408) slabB[17408,34816)
// lbuf[34816,35840) — K slab aliases slabA (sequential use, barrier between).
// ---------------------------------------------------------------------------
__global__ __launch_bounds__(256, 3) void attn_kernel(
    const __bf16* __restrict__ qws, const __bf16* __restrict__ kws,
    const __bf16* __restrict__ vtws, float* __restrict__ out)
{
    // XCD-aware bijective decode: bid = xcd + 8*j, j = 32*(group within XCD) + qt
    const int bid = blockIdx.x;
    const int xcd = bid & 7;
    const int j   = bid >> 3;            // 0..191
    const int g   = xcd * 6 + (j >> 5);  // (b,h) group 0..47
    const int qt  = j & 31;
    const int h   = g % NH;
    const int b   = g / NH;

    const int q0 = qt * 64;
    const int tid = threadIdx.x;

    __shared__ __align__(16) unsigned char smem[35840];
    __bf16* lds = (__bf16*)smem;                 // K slabs (hot loop)
    float* slabA = (float*)smem;                 // 64 x 68 f32 (epilogue)
    float* slabB = (float*)(smem + 17408);       // 64 x 68 f32
    float* lbuf  = (float*)(smem + 34816);       // 256 f32

    const size_t bh = (size_t)(b * NH + h);
    const int lane = tid & 63, w = tid >> 6, col = lane & 15, quad = lane >> 4;
    const int L = lane;

    // Q fragments (fragment-major layout; coalesced; R4-verified)
    bf16x8 qb0[4], qb1[4];
    {
        const __bf16* qp = qws + (size_t)bh * 131072 + (size_t)qt * 4096 + lane * 8;
#pragma unroll
        for (int nt = 0; nt < 4; ++nt) {
            qb0[nt] = *(const bf16x8*)(qp + nt * 1024);
            qb1[nt] = *(const bf16x8*)(qp + nt * 1024 + 512);
        }
    }

    // K staging source (XOR swizzle baked into SOURCE address; R3-verified)
    const __bf16* ksrc = kws + bh * (size_t)(NS * NDH)
                       + (size_t)(w * 32 + (L >> 3)) * NDH + ((L & 7) ^ (L >> 3)) * 8;
    const int kb_lds = w * 2048 + L * 8;           // elems

    // swizzled K LDS read offsets (elems) — R3-verified
    const int cx7 = col & 7;
    int ka_off[2][2];
#pragma unroll
    for (int mt = 0; mt < 2; ++mt) {
        const int base = w * 2048 + (mt * 16 + col) * 64;
        ka_off[mt][0] = base + ((quad)     ^ cx7) * 8;
        ka_off[mt][1] = base + ((quad + 4) ^ cx7) * 8;
    }

    // V fragment-major base (R4-verified)
    const __bf16* vb = vtws + (size_t)bh * 131072 + w * 2048 + lane * 8;

    float l[4] = {0.f, 0.f, 0.f, 0.f};
    f32x4 o[4][4];
#pragma unroll
    for (int dt = 0; dt < 4; ++dt)
#pragma unroll
        for (int nt = 0; nt < 4; ++nt) o[dt][nt] = (f32x4){0.f, 0.f, 0.f, 0.f};

#define KSTAGE_LOAD(kt) do { \
        const __bf16* _ks = ksrc + (size_t)(kt) * 8192; \
        kstg[0] = *(const uint4*)(_ks);        kstg[1] = *(const uint4*)(_ks + 512); \
        kstg[2] = *(const uint4*)(_ks + 1024); kstg[3] = *(const uint4*)(_ks + 1536); \
    } while (0)
#define KSTAGE_WRITE do { \
        *(uint4*)&lds[kb_lds]        = kstg[0]; *(uint4*)&lds[kb_lds + 512]  = kstg[1]; \
        *(uint4*)&lds[kb_lds + 1024] = kstg[2]; *(uint4*)&lds[kb_lds + 1536] = kstg[3]; \
    } while (0)
#define LOADK_LDS(ka) do { \
        ka[0][0] = *(const bf16x8*)&lds[ka_off[0][0]]; \
        ka[0][1] = *(const bf16x8*)&lds[ka_off[0][1]]; \
        ka[1][0] = *(const bf16x8*)&lds[ka_off[1][0]]; \
        ka[1][1] = *(const bf16x8*)&lds[ka_off[1][1]]; \
    } while (0)
#define LOADVG(dst, kt) do { \
        const __bf16* _p = vb + (size_t)(kt) * 8192; \
        dst[0] = *(const bf16x8*)(_p);        dst[1] = *(const bf16x8*)(_p + 512); \
        dst[2] = *(const bf16x8*)(_p + 1024); dst[3] = *(const bf16x8*)(_p + 1536); \
    } while (0)

    auto compute = [&](const bf16x8 (&ka)[2][2], const bf16x8 (&va)[4]) {
#pragma unroll
        for (int nt = 0; nt < 4; ++nt) {
            f32x4 sA = {0.f, 0.f, 0.f, 0.f};
            f32x4 sB = {0.f, 0.f, 0.f, 0.f};
            sA = MFMA16(ka[0][0], qb0[nt], sA); sA = MFMA16(ka[0][1], qb1[nt], sA);
            sB = MFMA16(ka[1][0], qb0[nt], sB); sB = MFMA16(ka[1][1], qb1[nt], sB);

            // direct exp2 — no max subtraction, fully lane-local
            const float p0 = __builtin_amdgcn_exp2f(sA[0]);
            const float p1 = __builtin_amdgcn_exp2f(sA[1]);
            const float p2 = __builtin_amdgcn_exp2f(sA[2]);
            const float p3 = __builtin_amdgcn_exp2f(sA[3]);
            const float p4 = __builtin_amdgcn_exp2f(sB[0]);
            const float p5 = __builtin_amdgcn_exp2f(sB[1]);
            const float p6 = __builtin_amdgcn_exp2f(sB[2]);
            const float p7 = __builtin_amdgcn_exp2f(sB[3]);
            l[nt] += ((p0 + p1) + (p2 + p3)) + ((p4 + p5) + (p6 + p7));

            union { u32 u[4]; bf16x8 v; } pb;   // B-frag: k_mfma = quad*8+mt*4+r
            pb.u[0] = packbf(p0, p1);
            pb.u[1] = packbf(p2, p3);
            pb.u[2] = packbf(p4, p5);
            pb.u[3] = packbf(p6, p7);

#pragma unroll
            for (int dt = 0; dt < 4; ++dt)
                o[dt][nt] = MFMA16(va[dt], pb.v, o[dt][nt]);
        }
    };

    // ---- prologue: stage K tile 0 into LDS; V tile 0 direct into regs ----
    uint4 kstg[4];
    bf16x8 vc[4], vn[4], ka[2][2];
    KSTAGE_LOAD(0);
    LOADVG(vc, 0);
    KSTAGE_WRITE;

    // 2-phase unrolled loop (NT even). In-order per-wave DS pipe makes the
    // read-then-overwrite of the wave-private K slab safe without barriers
    // (R3-proven pattern); each K stage has one compute phase of vmcnt slack
    // (L2-resident via swizzle).
    for (int kt2 = 0; kt2 < NT; kt2 += 2) {
        // phase A: compute tile kt2 (K from LDS, V from vc)
        KSTAGE_LOAD(kt2 + 1);
        LOADVG(vn, kt2 + 1);
        LOADK_LDS(ka);
        compute(ka, vc);
        KSTAGE_WRITE;                       // K tile kt2+1 -> slab

        // phase B: compute tile kt2+1 (K from LDS, V from vn)
        if (kt2 + 2 < NT) {
            KSTAGE_LOAD(kt2 + 2);
            LOADVG(vc, kt2 + 2);
        }
        LOADK_LDS(ka);
        compute(ka, vn);
        if (kt2 + 2 < NT) KSTAGE_WRITE;     // K tile kt2+2 -> slab
    }
#undef KSTAGE_LOAD
#undef KSTAGE_WRITE
#undef LOADK_LDS
#undef LOADVG

    // cross-quad l reduction (deferred from loop)
#pragma unroll
    for (int nt = 0; nt < 4; ++nt) {
        l[nt] += __shfl_xor(l[nt], 16, 64);
        l[nt] += __shfl_xor(l[nt], 32, 64);
    }

    // ---- split-K combine across the 4 waves (l only — no m state) ----
    __syncthreads();   // all waves done with K slabs; epilogue regions free
    if (quad == 0) {
#pragma unroll
        for (int nt = 0; nt < 4; ++nt)
            lbuf[w * 64 + nt * 16 + col] = l[nt];
    }
    __syncthreads();

    float scale[4];
#pragma unroll
    for (int nt = 0; nt < 4; ++nt) {
        const int qi = nt * 16 + col;
        const float Lt = (lbuf[qi] + lbuf[64 + qi]) + (lbuf[128 + qi] + lbuf[192 + qi]);
        scale[nt] = 1.0f / Lt;
    }
    __syncthreads();   // lbuf reads done before slab writes alias the region
#pragma unroll
    for (int dt = 0; dt < 4; ++dt)
#pragma unroll
        for (int nt = 0; nt < 4; ++nt) o[dt][nt] *= scale[nt];

    if (w == 0 || w == 2) {
        float* s = (w == 0) ? slabA : slabB;
#pragma unroll
        for (int dt = 0; dt < 4; ++dt)
#pragma unroll
            for (int nt = 0; nt < 4; ++nt)
                *(f32x4*)&s[(nt * 16 + col) * 68 + dt * 16 + quad * 4] = o[dt][nt];
    }
    __syncthreads();
    if (w == 1 || w == 3) {
        float* s = (w == 1) ? slabA : slabB;
#pragma unroll
        for (int dt = 0; dt < 4; ++dt)
#pragma unroll
            for (int nt = 0; nt < 4; ++nt) {
                f32x4* p = (f32x4*)&s[(nt * 16 + col) * 68 + dt * 16 + quad * 4];
                *p = *p + o[dt][nt];
            }
    }
    __syncthreads();

    const int qr = tid >> 2, fq = tid & 3;
#pragma unroll
    for (int j2 = 0; j2 < 4; ++j2) {
        const f32x4 a = *(const f32x4*)&slabA[qr * 68 + fq * 16 + j2 * 4];
        const f32x4 c = *(const f32x4*)&slabB[qr * 68 + fq * 16 + j2 * 4];
        *(f32x4*)&out[(size_t)(b * NS + q0 + qr) * ND + h * NDH + fq * 16 + j2 * 4] = a + c;
    }
}

extern "C" void kernel_launch(void* const* d_in, const int* in_sizes, int n_in,
                              void* d_out, int out_size, void* d_ws, size_t ws_size,
                              hipStream_t stream) {
    (void)in_sizes; (void)n_in; (void)out_size; (void)ws_size;
    const float* x  = (const float*)d_in[0];
    const float* wq = (const float*)d_in[1];
    const float* bq = (const float*)d_in[2];
    const float* wk = (const float*)d_in[3];
    const float* bk = (const float*)d_in[4];
    const float* wv = (const float*)d_in[5];
    const float* bv = (const float*)d_in[6];
    float* out = (float*)d_out;

    __bf16* qws  = (__bf16*)d_ws;
    __bf16* kws  = qws + (size_t)NB * NH * NS * NDH;
    __bf16* vtws = kws + (size_t)NB * NH * NS * NDH;

    dim3 grid(NS / 64, NH, NB);
    proj_kernel<<<grid, 256, 0, stream>>>(x, wq, bq, wk, bk, wv, bv, qws, kws, vtws);
    attn_kernel<<<dim3(NS / 64 * NH * NB), 256, 0, stream>>>(qws, kws, vtws, out);
}

// Round 6
// 168.395 us; speedup vs baseline: 1.6923x; 1.5634x over previous
//
#include <hip/hip_runtime.h>

#define NB 4
#define NS 2048
#define ND 768
#define NH 12
#define NDH 64
#define NT (NS / 128)
#define XPITCH 72
#define SSCALE 0.18033688011112043f   // (1/sqrt(64)) * log2(e)

typedef __bf16 bf16x8 __attribute__((ext_vector_type(8)));
typedef float  f32x4  __attribute__((ext_vector_type(4)));
typedef unsigned int u32;

#define MFMA16(a, b, c) __builtin_amdgcn_mfma_f32_16x16x32_bf16(a, b, c, 0, 0, 0)

__device__ __forceinline__ u32 packbf(float a, float b) {
    u32 ua = __builtin_bit_cast(u32, a) + 0x8000u;
    u32 ub = __builtin_bit_cast(u32, b) + 0x8000u;
    return __builtin_amdgcn_perm(ub, ua, 0x07060302u);
}

__device__ __forceinline__ bf16x8 cvt8(float4 a, float4 b) {
    union { u32 u[4]; bf16x8 v; } r;
    r.u[0] = packbf(a.x, a.y); r.u[1] = packbf(a.z, a.w);
    r.u[2] = packbf(b.x, b.y); r.u[3] = packbf(b.z, b.w);
    return r.v;
}

__device__ __forceinline__ __bf16 f2bf(float f) {
    u32 u = __builtin_bit_cast(u32, f) + 0x8000u;
    unsigned short s = (unsigned short)(u >> 16);
    return __builtin_bit_cast(__bf16, s);
}

// HW DMA global->LDS, 16B per lane. LDS dest must be the WAVE-UNIFORM lane-0
// base; HW adds lane*16B. Global source is per-lane.
__device__ __forceinline__ void gl16(const __bf16* g, __bf16* l) {
    __builtin_amdgcn_global_load_lds(
        (const __attribute__((address_space(1))) unsigned int*)g,
        (__attribute__((address_space(3))) unsigned int*)l,
        16, 0, 0);
}

// ---------------------------------------------------------------------------
// Workspace layouts — ALL fragment-major, ALL R4-hardware-verified:
//   Q: bh*131072 + qt*4096 + nt*1024 + j*512 + lane*8
//   K: bh*131072 + kt*8192 + w*2048 + mt*1024 + j*512 + lane*8
//   V: bh*131072 + kt*8192 + w*2048 + dt*512            + lane*8
// Every per-(wave,tile) block is 4KB contiguous -> DMA source chunks are
// contiguous 1KB per call; LDS stays LINEAR (lane*16B), ds_read_b128 at
// 16B/lane stride = 2-way bank alias = free (m136). No swizzle anywhere.
// ---------------------------------------------------------------------------

// ---------------------------------------------------------------------------
// Kernel 1: QKV projections — R4 VERBATIM (hardware-verified, fully
// coalesced fragment-major stores for Q, K, and V).
// ---------------------------------------------------------------------------
__global__ __launch_bounds__(256, 4) void proj_kernel(
    const float* __restrict__ x,
    const float* __restrict__ wq, const float* __restrict__ bq,
    const float* __restrict__ wk, const float* __restrict__ bk,
    const float* __restrict__ wv, const float* __restrict__ bv,
    __bf16* __restrict__ qws, __bf16* __restrict__ kws, __bf16* __restrict__ vtws)
{
    const int st = blockIdx.x, h = blockIdx.y, b = blockIdx.z;
    const int s0 = st * 64;
    const int tid = threadIdx.x;

    __shared__ __align__(16) __bf16 Xs[64 * XPITCH];
    __shared__ __align__(16) __bf16 Tv[64 * XPITCH];

    const int r = tid >> 2, f = tid & 3;
    const int lane = tid & 63, w = tid >> 6, col = lane & 15, quad = lane >> 4;

    const size_t wrow = (size_t)(h * NDH + w * 16 + col) * NDH;
    const float* wq0 = wq + wrow + quad * 8;
    const float* wk0 = wk + wrow + quad * 8;
    const float* wv0 = wv + wrow + quad * 8;
    const bf16x8 wqa0 = cvt8(*(const float4*)(wq0),      *(const float4*)(wq0 + 4));
    const bf16x8 wqa1 = cvt8(*(const float4*)(wq0 + 32), *(const float4*)(wq0 + 36));
    const bf16x8 wka0 = cvt8(*(const float4*)(wk0),      *(const float4*)(wk0 + 4));
    const bf16x8 wka1 = cvt8(*(const float4*)(wk0 + 32), *(const float4*)(wk0 + 36));
    const bf16x8 wva0 = cvt8(*(const float4*)(wv0),      *(const float4*)(wv0 + 4));
    const bf16x8 wva1 = cvt8(*(const float4*)(wv0 + 32), *(const float4*)(wv0 + 36));

    float bqs[4], bks[4], bvs[4];
#pragma unroll
    for (int rr = 0; rr < 4; ++rr) {
        const int e = h * NDH + w * 16 + quad * 4 + rr;
        bqs[rr] = bq[e] * SSCALE;
        bks[rr] = bk[e];
        bvs[rr] = bv[e];
    }

    const size_t bh = (size_t)(b * NH + h);

    {
        const float* xrow = x + (size_t)(b * NS + s0 + r) * ND + h * NDH + f * 16;
        const float4 v0 = *(const float4*)(xrow);
        const float4 v1 = *(const float4*)(xrow + 4);
        const float4 v2 = *(const float4*)(xrow + 8);
        const float4 v3 = *(const float4*)(xrow + 12);
        *(bf16x8*)&Xs[r * XPITCH + f * 16]     = cvt8(v0, v1);
        *(bf16x8*)&Xs[r * XPITCH + f * 16 + 8] = cvt8(v2, v3);
    }
    __syncthreads();

    // lane-constant pieces of the fragment-layout address (e-side):
    // e0 = w*16 + quad*4 = 32*jj + 8*qa + 4*hf
    const int e0 = w * 16 + quad * 4;
    const int jj = e0 >> 5;            // j (0/1)
    const int qa = (e0 >> 3) & 3;      // quad_attn
    const int hf = (e0 >> 2) & 1;      // which uint2 half of the 16B chunk
    const int Lf = qa * 16 + col;      // fragment lane
    const int kt = st >> 1;            // 128-row K-tile index

#pragma unroll
    for (int nt = 0; nt < 4; ++nt) {
        const bf16x8 xb0 = *(const bf16x8*)&Xs[(nt * 16 + col) * XPITCH + quad * 8];
        const bf16x8 xb1 = *(const bf16x8*)&Xs[(nt * 16 + col) * XPITCH + 32 + quad * 8];
        f32x4 aq = {0.f, 0.f, 0.f, 0.f};
        f32x4 ak = {0.f, 0.f, 0.f, 0.f};
        f32x4 av = {0.f, 0.f, 0.f, 0.f};
        aq = MFMA16(wqa0, xb0, aq); aq = MFMA16(wqa1, xb1, aq);
        ak = MFMA16(wka0, xb0, ak); ak = MFMA16(wka1, xb1, ak);
        av = MFMA16(wva0, xb0, av); av = MFMA16(wva1, xb1, av);

        union { u32 u[2]; uint2 v; } pq, pk;
        pq.u[0] = packbf(fmaf(aq[0], SSCALE, bqs[0]), fmaf(aq[1], SSCALE, bqs[1]));
        pq.u[1] = packbf(fmaf(aq[2], SSCALE, bqs[2]), fmaf(aq[3], SSCALE, bqs[3]));
        pk.u[0] = packbf(ak[0] + bks[0], ak[1] + bks[1]);
        pk.u[1] = packbf(ak[2] + bks[2], ak[3] + bks[3]);

        // fragment-major stores (R4-verified)
        const int wa = (st & 1) * 2 + (nt >> 1);   // attn wave owning this row
        const int mt = nt & 1;
        const size_t kidx = ((((((size_t)bh * 16 + kt) * 4 + wa) * 2 + mt) * 2 + jj) * 64 + Lf) * 8 + hf * 4;
        const size_t qidx = (((((size_t)bh * 32 + st) * 4 + nt) * 2 + jj) * 64 + Lf) * 8 + hf * 4;
        *(uint2*)(kws + kidx) = pk.v;
        *(uint2*)(qws + qidx) = pq.v;

        const int pos = ((nt >> 1) << 5) + ((col >> 2) << 3) + ((nt & 1) << 2) + (col & 3);
#pragma unroll
        for (int rr = 0; rr < 4; ++rr)
            Tv[(w * 16 + quad * 4 + rr) * XPITCH + pos] = f2bf(av[rr] + bvs[rr]);
    }
    __syncthreads();

    {
        const uint4 v0 = *(const uint4*)&Tv[r * XPITCH + f * 16];
        const uint4 v1 = *(const uint4*)&Tv[r * XPITCH + f * 16 + 8];
        // thread (r,f) holds V^T[d=r][s0 + f*16 .. +15] = two 8-s chunks (R4-verified)
        const int wv_ = (st & 1) * 2 + (f >> 1);
        const int dtv = r >> 4;
        const int colv = r & 15;
        const int L0 = ((f & 1) * 2 + 0) * 16 + colv;
        const int L1 = ((f & 1) * 2 + 1) * 16 + colv;
        const size_t vbase = (((size_t)bh * 16 + kt) * 4 + wv_) * 4 + dtv;
        *(uint4*)(vtws + (vbase * 64 + L0) * 8) = v0;
        *(uint4*)(vtws + (vbase * 64 + L1) * 8) = v1;
    }
}

// ---------------------------------------------------------------------------
// Kernel 2: flash attention WITHOUT online max (scores statically bounded;
// exp2 direct). ZERO-REGISTER staging via global_load_lds DMA:
//   - fragment-major K/V in global (R4-verified addresses), contiguous 1KB
//     chunks -> DMA source fully coalesced; LDS linear (lane*16B dest).
//   - NO staging registers (R2/R4/R5 lesson: (256,3) has ~20 spare regs;
//     kstg/vstg/double-buffer fragments all spilled. Peak live now
//     qb32 + o64(acc) + ka/va32 + addr ~= 140 < 168).
//   - hot loop DS ops: 8 ds_read_b128 only (R3 had 8 reads + 8 writes);
//     stride-16B/lane reads = 2-way bank alias = free, no swizzle.
//   - single-buffered wave-private slab; sync: ds_read -> lgkmcnt(0) (+SB)
//     -> issue DMA(kt+1) -> compute -> loop-top vmcnt(0) (+SB). DMA latency
//     (L2-resident via XCD swizzle) hides under ~900cy compute.
// s_setprio OUT (R3: +7us). XCD-bijective decode kept (R3: FETCH 109->24MB).
// launch_bounds(256,3) — NEVER 4: VGPR_Count(84) excludes the 64 acc regs.
// LDS: K [0,16K) | V [16K,32K) | lbuf [34816,35840); epilogue slabs alias.
// ---------------------------------------------------------------------------
__global__ __launch_bounds__(256, 3) void attn_kernel(
    const __bf16* __restrict__ qws, const __bf16* __restrict__ kws,
    const __bf16* __restrict__ vtws, float* __restrict__ out)
{
    // XCD-aware bijective decode: bid = xcd + 8*j, j = 32*(group within XCD) + qt
    const int bid = blockIdx.x;
    const int xcd = bid & 7;
    const int j   = bid >> 3;            // 0..191
    const int g   = xcd * 6 + (j >> 5);  // (b,h) group 0..47
    const int qt  = j & 31;
    const int h   = g % NH;
    const int b   = g / NH;

    const int q0 = qt * 64;
    const int tid = threadIdx.x;

    __shared__ __align__(16) unsigned char smem[36864];
    __bf16* ldsK = (__bf16*)smem;                // 16 KB, wave w at [w*2048, +2048) elems
    __bf16* ldsV = (__bf16*)(smem + 16384);      // 16 KB
    float* slabA = (float*)smem;                 // 64 x 68 f32 (epilogue, aliases)
    float* slabB = (float*)(smem + 17408);       // 64 x 68 f32
    float* lbuf  = (float*)(smem + 34816);       // 256 f32

    const size_t bh = (size_t)(b * NH + h);
    const int lane = tid & 63, w = tid >> 6, col = lane & 15, quad = lane >> 4;

    // Q fragments (fragment-major; coalesced; R4-verified)
    bf16x8 qb0[4], qb1[4];
    {
        const __bf16* qp = qws + (size_t)bh * 131072 + (size_t)qt * 4096 + lane * 8;
#pragma unroll
        for (int nt = 0; nt < 4; ++nt) {
            qb0[nt] = *(const bf16x8*)(qp + nt * 1024);
            qb1[nt] = *(const bf16x8*)(qp + nt * 1024 + 512);
        }
    }

    // fragment-major global bases (per-lane) and LDS bases
    const __bf16* kg = kws  + (size_t)bh * 131072 + w * 2048 + lane * 8;  // per-lane src
    const __bf16* vg = vtws + (size_t)bh * 131072 + w * 2048 + lane * 8;
    __bf16* lk  = ldsK + w * 2048;              // wave-uniform DMA dest base
    __bf16* lv  = ldsV + w * 2048;
    const __bf16* lkr = lk + lane * 8;          // per-lane read base
    const __bf16* lvr = lv + lane * 8;

    float l[4] = {0.f, 0.f, 0.f, 0.f};
    f32x4 o[4][4];
#pragma unroll
    for (int dt = 0; dt < 4; ++dt)
#pragma unroll
        for (int nt = 0; nt < 4; ++nt) o[dt][nt] = (f32x4){0.f, 0.f, 0.f, 0.f};

    // ---- prologue: DMA tile 0 into wave-private slabs (no regs, no barrier)
#pragma unroll
    for (int i = 0; i < 4; ++i) gl16(kg + i * 512, lk + i * 512);
#pragma unroll
    for (int i = 0; i < 4; ++i) gl16(vg + i * 512, lv + i * 512);

    for (int kt = 0; kt < NT; ++kt) {
        // DMA for this tile (issued last iteration / prologue) must have landed
        asm volatile("s_waitcnt vmcnt(0)" ::: "memory");
        __builtin_amdgcn_sched_barrier(0);

        bf16x8 ka[2][2], va[4];
        ka[0][0] = *(const bf16x8*)(lkr);
        ka[0][1] = *(const bf16x8*)(lkr + 512);
        ka[1][0] = *(const bf16x8*)(lkr + 1024);
        ka[1][1] = *(const bf16x8*)(lkr + 1536);
        va[0] = *(const bf16x8*)(lvr);
        va[1] = *(const bf16x8*)(lvr + 512);
        va[2] = *(const bf16x8*)(lvr + 1024);
        va[3] = *(const bf16x8*)(lvr + 1536);

        // reads must COMPLETE before the DMA may overwrite the slab
        asm volatile("s_waitcnt lgkmcnt(0)" ::: "memory");
        __builtin_amdgcn_sched_barrier(0);

        if (kt + 1 < NT) {
            const __bf16* kgn = kg + (size_t)(kt + 1) * 8192;
            const __bf16* vgn = vg + (size_t)(kt + 1) * 8192;
#pragma unroll
            for (int i = 0; i < 4; ++i) gl16(kgn + i * 512, lk + i * 512);
#pragma unroll
            for (int i = 0; i < 4; ++i) gl16(vgn + i * 512, lv + i * 512);
        }

#pragma unroll
        for (int nt = 0; nt < 4; ++nt) {
            f32x4 sA = {0.f, 0.f, 0.f, 0.f};
            f32x4 sB = {0.f, 0.f, 0.f, 0.f};
            sA = MFMA16(ka[0][0], qb0[nt], sA); sA = MFMA16(ka[0][1], qb1[nt], sA);
            sB = MFMA16(ka[1][0], qb0[nt], sB); sB = MFMA16(ka[1][1], qb1[nt], sB);

            // direct exp2 — no max subtraction, fully lane-local
            const float p0 = __builtin_amdgcn_exp2f(sA[0]);
            const float p1 = __builtin_amdgcn_exp2f(sA[1]);
            const float p2 = __builtin_amdgcn_exp2f(sA[2]);
            const float p3 = __builtin_amdgcn_exp2f(sA[3]);
            const float p4 = __builtin_amdgcn_exp2f(sB[0]);
            const float p5 = __builtin_amdgcn_exp2f(sB[1]);
            const float p6 = __builtin_amdgcn_exp2f(sB[2]);
            const float p7 = __builtin_amdgcn_exp2f(sB[3]);
            l[nt] += ((p0 + p1) + (p2 + p3)) + ((p4 + p5) + (p6 + p7));

            union { u32 u[4]; bf16x8 v; } pb;   // B-frag: k_mfma = quad*8+mt*4+r
            pb.u[0] = packbf(p0, p1);
            pb.u[1] = packbf(p2, p3);
            pb.u[2] = packbf(p4, p5);
            pb.u[3] = packbf(p6, p7);

#pragma unroll
            for (int dt = 0; dt < 4; ++dt)
                o[dt][nt] = MFMA16(va[dt], pb.v, o[dt][nt]);
        }
    }

    // cross-quad l reduction (deferred from loop)
#pragma unroll
    for (int nt = 0; nt < 4; ++nt) {
        l[nt] += __shfl_xor(l[nt], 16, 64);
        l[nt] += __shfl_xor(l[nt], 32, 64);
    }

    // ---- split-K combine across the 4 waves (l only — no m state) ----
    __syncthreads();   // all waves done with K/V slabs; epilogue regions free
    if (quad == 0) {
#pragma unroll
        for (int nt = 0; nt < 4; ++nt)
            lbuf[w * 64 + nt * 16 + col] = l[nt];
    }
    __syncthreads();

    float scale[4];
#pragma unroll
    for (int nt = 0; nt < 4; ++nt) {
        const int qi = nt * 16 + col;
        const float Lt = (lbuf[qi] + lbuf[64 + qi]) + (lbuf[128 + qi] + lbuf[192 + qi]);
        scale[nt] = 1.0f / Lt;
    }
    __syncthreads();   // lbuf reads done before slab writes alias the region
#pragma unroll
    for (int dt = 0; dt < 4; ++dt)
#pragma unroll
        for (int nt = 0; nt < 4; ++nt) o[dt][nt] *= scale[nt];

    if (w == 0 || w == 2) {
        float* s = (w == 0) ? slabA : slabB;
#pragma unroll
        for (int dt = 0; dt < 4; ++dt)
#pragma unroll
            for (int nt = 0; nt < 4; ++nt)
                *(f32x4*)&s[(nt * 16 + col) * 68 + dt * 16 + quad * 4] = o[dt][nt];
    }
    __syncthreads();
    if (w == 1 || w == 3) {
        float* s = (w == 1) ? slabA : slabB;
#pragma unroll
        for (int dt = 0; dt < 4; ++dt)
#pragma unroll
            for (int nt = 0; nt < 4; ++nt) {
                f32x4* p = (f32x4*)&s[(nt * 16 + col) * 68 + dt * 16 + quad * 4];
                *p = *p + o[dt][nt];
            }
    }
    __syncthreads();

    const int qr = tid >> 2, fq = tid & 3;
#pragma unroll
    for (int j2 = 0; j2 < 4; ++j2) {
        const f32x4 a = *(const f32x4*)&slabA[qr * 68 + fq * 16 + j2 * 4];
        const f32x4 c = *(const f32x4*)&slabB[qr * 68 + fq * 16 + j2 * 4];
        *(f32x4*)&out[(size_t)(b * NS + q0 + qr) * ND + h * NDH + fq * 16 + j2 * 4] = a + c;
    }
}

extern "C" void kernel_launch(void* const* d_in, const int* in_sizes, int n_in,
                              void* d_out, int out_size, void* d_ws, size_t ws_size,
                              hipStream_t stream) {
    (void)in_sizes; (void)n_in; (void)out_size; (void)ws_size;
    const float* x  = (const float*)d_in[0];
    const float* wq = (const float*)d_in[1];
    const float* bq = (const float*)d_in[2];
    const float* wk = (const float*)d_in[3];
    const float* bk = (const float*)d_in[4];
    const float* wv = (const float*)d_in[5];
    const float* bv = (const float*)d_in[6];
    float* out = (float*)d_out;

    __bf16* qws  = (__bf16*)d_ws;
    __bf16* kws  = qws + (size_t)NB * NH * NS * NDH;
    __bf16* vtws = kws + (size_t)NB * NH * NS * NDH;

    dim3 grid(NS / 64, NH, NB);
    proj_kernel<<<grid, 256, 0, stream>>>(x, wq, bq, wk, bk, wv, bv, qws, kws, vtws);
    attn_kernel<<<dim3(NS / 64 * NH * NB), 256, 0, stream>>>(qws, kws, vtws, out);
}